// Round 11
// baseline (246.377 us; speedup 1.0000x reference)
//
#include <hip/hip_runtime.h>
#include <math.h>

#define BB 8
#define NCC 1024
#define NTT 1024
#define HH 128
#define DYY 32
#define LOG2E 1.44269504088896340736f

// LDS arena (floats):
//   yc0/yc1 [    0, 8192)  attn yc tiles, 2 x (128n x 32d)
//   xc0/xc1 [ 8192, 8960)  attn xc tiles, 2 x 384
//   sigl    [ 8960, 9056)  sig*log2e for the block's 32 targets
//   hbuf    [ 9056, 13184) MLP activations 32x129 (stride 129, conflict-free)
//   red     [13184, 16256) MLP L3 reduction scratch (32jg x 32p x 3)
// epilogue aliases [0, 8704) as sacc(8x32x33)+sl(256) after the last tile barrier.
#define YC0 0
#define XC0 8192
#define SIGL 8960
#define HB 9056
#define RED 13184
#define SMEMN 16256
#define HSTRIDE 129

// ---------------- fused kernel, 1024 threads = 4 waves/SIMD from ONE block ----------------
// Grid 256 x 1024 thr; block = 32 targets of one batch. r10 lesson: 2-block/CU
// co-residency never materialized and redundant MLP doubled the dominant cost
// (MLP ~37 of 56 µs). This round: same work, 2x the waves, zero redundancy.
// Phase 1: thread = (jg 0..31, p 0..31), 4 cols each, depth-8 W pipeline
// (r5 lesson). Phase 2: 16 waves x 8n per 128-tile, LDS-staged lane-varying
// float4 loads (r6 lesson), prefetch distance 2, no pointer arrays into
// __shared__ (r7 lesson). P<=0 => exp(P)<=1: no max subtraction; two-stage
// wave combine in LDS, one output element per thread.
__global__ __launch_bounds__(1024) void k_fused(const float* __restrict__ xc,
                                                const float* __restrict__ yc,
                                                const float* __restrict__ xt,
                                                const float* __restrict__ W0,
                                                const float* __restrict__ b0,
                                                const float* __restrict__ W1,
                                                const float* __restrict__ b1,
                                                const float* __restrict__ W2,
                                                const float* __restrict__ b2,
                                                const float* __restrict__ W3,
                                                const float* __restrict__ b3,
                                                float* __restrict__ out) {
    const int tid = threadIdx.x;
    const int t0 = blockIdx.x * 32;      // target base
    const int b = blockIdx.x >> 5;       // batch

    __shared__ float smem[SMEMN];        // 63.5 KB

    const float4* __restrict__ ycG = (const float4*)(yc + (size_t)b * NCC * DYY);
    const float4* __restrict__ xcG = (const float4*)(xc + (size_t)b * NCC * 3);

    // ---- issue tile-0/1 staging loads now (land during MLP compute) ----
    float4 y0 = ycG[tid], y1 = ycG[1024 + tid];
    float4 xp0, xp1;
    if (tid < 96) { xp0 = xcG[tid]; xp1 = xcG[96 + tid]; }

    // ================= phase 1: MLP =================
    {
        const int jg = tid >> 5;         // 0..31 col-group (4 cols)
        const int p = tid & 31;          // 0..31 point
        const int j0 = jg * 4;

        // ---- L0 ----
        const float* xr = xt + (size_t)(t0 + p) * 3;
        float x0 = xr[0], x1 = xr[1], x2 = xr[2];
        float o[4];
#pragma unroll
        for (int jj = 0; jj < 4; ++jj) {
            int j = j0 + jj;
            float a = b0[j];
            a = fmaf(x0, W0[0 * HH + j], a);
            a = fmaf(x1, W0[1 * HH + j], a);
            a = fmaf(x2, W0[2 * HH + j], a);
            o[jj] = fmaxf(a, 0.f);
        }
#pragma unroll
        for (int jj = 0; jj < 4; ++jj) smem[HB + p * HSTRIDE + j0 + jj] = o[jj];

        // ---- park attn tiles 0/1 (frees prefetch VGPRs) ----
        ((float4*)(smem + YC0))[tid] = y0;
        ((float4*)(smem + YC0 + 4096))[tid] = y1;
        if (tid < 96) {
            ((float4*)(smem + XC0))[tid] = xp0;
            ((float4*)(smem + XC0 + 384))[tid] = xp1;
        }
        __syncthreads();

        // ---- L1, L2: depth-8 pipelined W stream, 1 float4/thread/k ----
        for (int l = 0; l < 2; ++l) {
            const float* __restrict__ W = (l == 0) ? W1 : W2;
            const float* __restrict__ bi = (l == 0) ? b1 : b2;
            const float4* __restrict__ Wv = (const float4*)W;   // [k][32 float4]
            float acc0 = bi[j0 + 0], acc1 = bi[j0 + 1];
            float acc2 = bi[j0 + 2], acc3 = bi[j0 + 3];

            float4 wv[8];
            float hv[8];
#pragma unroll
            for (int i = 0; i < 8; ++i) {
                wv[i] = Wv[i * 32 + jg];
                hv[i] = smem[HB + p * HSTRIDE + i];
            }
            for (int k = 0; k < 120; k += 8) {
#pragma unroll
                for (int i = 0; i < 8; ++i) {
                    float4 cw = wv[i];
                    float ch = hv[i];
                    int kn = k + 8 + i;
                    wv[i] = Wv[kn * 32 + jg];
                    hv[i] = smem[HB + p * HSTRIDE + kn];
                    acc0 = fmaf(ch, cw.x, acc0);
                    acc1 = fmaf(ch, cw.y, acc1);
                    acc2 = fmaf(ch, cw.z, acc2);
                    acc3 = fmaf(ch, cw.w, acc3);
                }
            }
#pragma unroll
            for (int i = 0; i < 8; ++i) {       // peeled last chunk
                float4 cw = wv[i];
                float ch = hv[i];
                acc0 = fmaf(ch, cw.x, acc0);
                acc1 = fmaf(ch, cw.y, acc1);
                acc2 = fmaf(ch, cw.z, acc2);
                acc3 = fmaf(ch, cw.w, acc3);
            }
            __syncthreads();                    // hbuf reads complete
            o[0] = fmaxf(acc0, 0.f);
            o[1] = fmaxf(acc1, 0.f);
            o[2] = fmaxf(acc2, 0.f);
            o[3] = fmaxf(acc3, 0.f);
            if (l == 0) {
#pragma unroll
                for (int jj = 0; jj < 4; ++jj)
                    smem[HB + p * HSTRIDE + j0 + jj] = o[jj];
                __syncthreads();
            }
        }

        // ---- L3 + exp -> sig*log2e in LDS ----
        float p0 = 0.f, p1 = 0.f, p2 = 0.f;
#pragma unroll
        for (int jj = 0; jj < 4; ++jj) {
            int j = j0 + jj;
            p0 = fmaf(o[jj], W3[j * 3 + 0], p0);
            p1 = fmaf(o[jj], W3[j * 3 + 1], p1);
            p2 = fmaf(o[jj], W3[j * 3 + 2], p2);
        }
        smem[RED + (jg * 32 + p) * 3 + 0] = p0;   // bank=(3p+c)%32: conflict-free
        smem[RED + (jg * 32 + p) * 3 + 1] = p1;
        smem[RED + (jg * 32 + p) * 3 + 2] = p2;
        __syncthreads();
        if (tid < 96) {
            int r = tid / 3, c = tid - r * 3;
            float v = b3[c];
#pragma unroll
            for (int g = 0; g < 32; ++g) v += smem[RED + (g * 32 + r) * 3 + c];
            smem[SIGL + r * 3 + c] = __expf(v) * LOG2E;
        }
        __syncthreads();
    }

    // ================= phase 2: attention =================
    const int w = tid >> 6;          // 0..15 wave = n-subchunk
    const int lane = tid & 63;
    const int tl = lane & 31;        // target within block
    const int dg = lane >> 5;        // 0..1 d-half

    const float s0 = smem[SIGL + tl * 3 + 0];
    const float s1 = smem[SIGL + tl * 3 + 1];
    const float s2 = smem[SIGL + tl * 3 + 2];
    const size_t t = (size_t)t0 + tl;
    const float a0 = xt[t * 3 + 0], a1 = xt[t * 3 + 1], a2 = xt[t * 3 + 2];

    float acc[16];
#pragma unroll
    for (int i = 0; i < 16; ++i) acc[i] = 0.f;
    float l = 0.f;

    for (int tile = 0; tile < 8; ++tile) {
        const int cur = tile & 1;
        float4 yn, xn;
        if (tile < 6) {                       // prefetch tile+2 (distance 2)
            yn = ycG[(tile + 2) * 1024 + tid];
            if (tid < 96) xn = xcG[(tile + 2) * 96 + tid];
        }

        const float* yb = smem + YC0 + cur * 4096;
        const float* xb = smem + XC0 + cur * 384;
#pragma unroll
        for (int i = 0; i < 8; ++i) {
            const int nn = w * 8 + i;
            float d0 = xb[nn * 3 + 0] - a0;
            float d1 = xb[nn * 3 + 1] - a1;
            float d2 = xb[nn * 3 + 2] - a2;
            float pp = fmaf(s0, d0 * d0, fmaf(s1, d1 * d1, s2 * (d2 * d2)));
            float e = exp2f(-pp);
            l += e;
            const float4* yv = (const float4*)(yb + nn * DYY + dg * 16);
            float4 q0 = yv[0], q1 = yv[1], q2 = yv[2], q3 = yv[3];
            acc[0]  = fmaf(e, q0.x, acc[0]);
            acc[1]  = fmaf(e, q0.y, acc[1]);
            acc[2]  = fmaf(e, q0.z, acc[2]);
            acc[3]  = fmaf(e, q0.w, acc[3]);
            acc[4]  = fmaf(e, q1.x, acc[4]);
            acc[5]  = fmaf(e, q1.y, acc[5]);
            acc[6]  = fmaf(e, q1.z, acc[6]);
            acc[7]  = fmaf(e, q1.w, acc[7]);
            acc[8]  = fmaf(e, q2.x, acc[8]);
            acc[9]  = fmaf(e, q2.y, acc[9]);
            acc[10] = fmaf(e, q2.z, acc[10]);
            acc[11] = fmaf(e, q2.w, acc[11]);
            acc[12] = fmaf(e, q3.x, acc[12]);
            acc[13] = fmaf(e, q3.y, acc[13]);
            acc[14] = fmaf(e, q3.z, acc[14]);
            acc[15] = fmaf(e, q3.w, acc[15]);
        }
        __syncthreads();                      // tile reads done
        if (tile < 6) {
            ((float4*)(smem + YC0 + cur * 4096))[tid] = yn;
            if (tid < 96) ((float4*)(smem + XC0 + cur * 384))[tid] = xn;
            __syncthreads();
        }
    }

    // ---- two-stage combine in LDS (aliases tile buffers), normalize, write ----
    // sacc[(w'*32+tl)*33 + dg*16+i] (8448 floats), sl at 8448 (256 floats).
    if (w >= 8) {                             // stage A: upper 8 waves deposit
#pragma unroll
        for (int i = 0; i < 16; ++i)
            smem[((w - 8) * 32 + tl) * 33 + dg * 16 + i] = acc[i];
        if (dg == 0) smem[8448 + (w - 8) * 32 + tl] = l;
    }
    __syncthreads();
    if (w < 8) {                              // stage B: lower 8 RMW-add (1:1 slots)
#pragma unroll
        for (int i = 0; i < 16; ++i)
            smem[(w * 32 + tl) * 33 + dg * 16 + i] += acc[i];
        if (dg == 0) smem[8448 + w * 32 + tl] += l;
    }
    __syncthreads();

    {
        const int rtl = tid >> 5, d = tid & 31;   // one output element per thread
        float s = 0.f, lsum = 0.f;
#pragma unroll
        for (int ww = 0; ww < 8; ++ww) {
            s += smem[(ww * 32 + rtl) * 33 + d];
            lsum += smem[8448 + ww * 32 + rtl];
        }
        out[(size_t)(t0 + rtl) * DYY + d] = s / lsum;
    }
}

extern "C" void kernel_launch(void* const* d_in, const int* in_sizes, int n_in,
                              void* d_out, int out_size, void* d_ws, size_t ws_size,
                              hipStream_t stream) {
    const float* xc = (const float*)d_in[0];
    const float* yc = (const float*)d_in[1];
    const float* xt = (const float*)d_in[2];
    const float* W0 = (const float*)d_in[3];
    const float* b0 = (const float*)d_in[4];
    const float* W1 = (const float*)d_in[5];
    const float* b1 = (const float*)d_in[6];
    const float* W2 = (const float*)d_in[7];
    const float* b2 = (const float*)d_in[8];
    const float* W3 = (const float*)d_in[9];
    const float* b3 = (const float*)d_in[10];
    float* out = (float*)d_out;

    k_fused<<<dim3(BB * NTT / 32), dim3(1024), 0, stream>>>(xc, yc, xt, W0, b0,
                                                            W1, b1, W2, b2, W3,
                                                            b3, out);
}

// Round 12
// 114.669 us; speedup vs baseline: 2.1486x; 2.1486x over previous
//
#include <hip/hip_runtime.h>
#include <math.h>

#define BB 8
#define NCC 1024
#define NTT 1024
#define HH 128
#define DYY 32
#define LOG2E 1.44269504088896340736f

// LDS arena: 8192 floats = 32 KB EXACTLY. r10/r11 lesson: 42.5-63.5 KB arenas
// pin occupancy at 1 block/CU (64-KB-per-CU model); <=32 KB admits 2 blocks.
//   phase 1: hbuf[HB,4128) red[RED,1536) Wbuf[WB,2048) sigl[SIGL,96)
//   phase 2: yc tiles [YCS, 2x2048) (aliases hbuf), xc [XCS, 2x192), sigl
//   epilogue: sacc [0,4224) + sl [4224,4352) (aliases yc tiles)
#define HB    0
#define RED   4128
#define XCS   5664
#define SIGL  6048
#define WB    6144
#define YCS   0
#define SL    4224
#define HSTRIDE 129

// ---------------- fused kernel ----------------
// 256 blocks x 512 threads (r9 proven shape: VGPR 88, no spill; r11 lesson:
// 1024-thread blocks force a 64-VGPR budget and spill catastrophically).
// Phase 1 MLP: thread=(jg 0..15, p 0..31), 8 cols. W streamed through LDS in
// 8-k chunks (GEMM-style) with distance-2 prefetch and ONE barrier per chunk
// (with 2 buffers + distance 2, the write of chunk c+2 after barrier(c) is
// ordered against its readers by barrier(c+1) — second barrier redundant).
// Phase 2 attn: 16 tiles of 64 n staged the same way. r6 lesson: all staging
// loads lane-varying. r7 lesson: no pointer arrays into __shared__.
// P<=0 (sig>0) => exp(P)<=1: no max subtraction; partials sum in LDS.
__global__ __launch_bounds__(512) void k_fused(const float* __restrict__ xc,
                                               const float* __restrict__ yc,
                                               const float* __restrict__ xt,
                                               const float* __restrict__ W0,
                                               const float* __restrict__ b0,
                                               const float* __restrict__ W1,
                                               const float* __restrict__ b1,
                                               const float* __restrict__ W2,
                                               const float* __restrict__ b2,
                                               const float* __restrict__ W3,
                                               const float* __restrict__ b3,
                                               float* __restrict__ out) {
    const int tid = threadIdx.x;
    const int t0 = blockIdx.x * 32;      // target base
    const int b = blockIdx.x >> 5;       // batch

    __shared__ float smem[8192];         // 32 KB

    const float4* __restrict__ ycG = (const float4*)(yc + (size_t)b * NCC * DYY);
    const float4* __restrict__ xcG = (const float4*)(xc + (size_t)b * NCC * 3);

    // ================= phase 1: MLP =================
    {
        const int jg = tid >> 5;         // 0..15 col-group (8 cols)
        const int p = tid & 31;          // 0..31 point
        const int j0 = jg * 8;

        // ---- L0 ----
        const float* xr = xt + (size_t)(t0 + p) * 3;
        float x0 = xr[0], x1 = xr[1], x2 = xr[2];
        float o[8];
#pragma unroll
        for (int jj = 0; jj < 8; ++jj) {
            int j = j0 + jj;
            float a = b0[j];
            a = fmaf(x0, W0[0 * HH + j], a);
            a = fmaf(x1, W0[1 * HH + j], a);
            a = fmaf(x2, W0[2 * HH + j], a);
            o[jj] = fmaxf(a, 0.f);
        }
#pragma unroll
        for (int jj = 0; jj < 8; ++jj) smem[HB + p * HSTRIDE + j0 + jj] = o[jj];

        // ---- L1, L2: W via LDS chunks (8 k-rows = 1024 floats per chunk) ----
        for (int l = 0; l < 2; ++l) {
            const float4* __restrict__ Wv = (const float4*)((l == 0) ? W1 : W2);
            const float* __restrict__ bi = (l == 0) ? b1 : b2;
            float acc[8];
#pragma unroll
            for (int jj = 0; jj < 8; ++jj) acc[jj] = bi[j0 + jj];

            if (tid < 256) {             // stage chunks 0,1 (coalesced float4)
                ((float4*)(smem + WB))[tid] = Wv[tid];
                ((float4*)(smem + WB + 1024))[tid] = Wv[256 + tid];
            }
            __syncthreads();

            for (int c = 0; c < 16; ++c) {
                float4 wpre;
                if (c < 14 && tid < 256) wpre = Wv[(c + 2) * 256 + tid];
                const float* wbuf = smem + WB + (c & 1) * 1024;
#pragma unroll
                for (int kk = 0; kk < 8; ++kk) {
                    const int k = c * 8 + kk;
                    float ch = smem[HB + p * HSTRIDE + k];
                    const float4* wr = (const float4*)(wbuf + kk * HH + j0);
                    float4 ca = wr[0], cb = wr[1];
                    acc[0] = fmaf(ch, ca.x, acc[0]);
                    acc[1] = fmaf(ch, ca.y, acc[1]);
                    acc[2] = fmaf(ch, ca.z, acc[2]);
                    acc[3] = fmaf(ch, ca.w, acc[3]);
                    acc[4] = fmaf(ch, cb.x, acc[4]);
                    acc[5] = fmaf(ch, cb.y, acc[5]);
                    acc[6] = fmaf(ch, cb.z, acc[6]);
                    acc[7] = fmaf(ch, cb.w, acc[7]);
                }
                __syncthreads();          // chunk reads done
                if (c < 14 && tid < 256)  // write chunk c+2 into freed buffer
                    ((float4*)(smem + WB + (c & 1) * 1024))[tid] = wpre;
            }

#pragma unroll
            for (int jj = 0; jj < 8; ++jj) o[jj] = fmaxf(acc[jj], 0.f);
            if (l == 0) {
#pragma unroll
                for (int jj = 0; jj < 8; ++jj)
                    smem[HB + p * HSTRIDE + j0 + jj] = o[jj];
                __syncthreads();          // h writes visible for layer 2
            }
        }

        // ---- L3 + exp -> sig*log2e in LDS ----
        float p0 = 0.f, p1 = 0.f, p2 = 0.f;
#pragma unroll
        for (int jj = 0; jj < 8; ++jj) {
            int j = j0 + jj;
            p0 = fmaf(o[jj], W3[j * 3 + 0], p0);
            p1 = fmaf(o[jj], W3[j * 3 + 1], p1);
            p2 = fmaf(o[jj], W3[j * 3 + 2], p2);
        }
        smem[RED + (jg * 32 + p) * 3 + 0] = p0;   // bank=(3p+c)%32: conflict-free
        smem[RED + (jg * 32 + p) * 3 + 1] = p1;
        smem[RED + (jg * 32 + p) * 3 + 2] = p2;
        __syncthreads();
        if (tid < 96) {
            int r = tid / 3, cidx = tid - r * 3;
            float v = b3[cidx];
#pragma unroll
            for (int g = 0; g < 16; ++g) v += smem[RED + (g * 32 + r) * 3 + cidx];
            smem[SIGL + r * 3 + cidx] = __expf(v) * LOG2E;
        }
        __syncthreads();                  // sigl ready; hbuf now dead
    }

    // ================= phase 2: attention (16 tiles of 64 n) =================
    const int w = tid >> 6;          // 0..7 wave: n-range [w*8, w*8+8) per tile
    const int lane = tid & 63;
    const int tl = lane & 31;        // target within block
    const int dg = lane >> 5;        // 0..1 d-half

    const float s0 = smem[SIGL + tl * 3 + 0];
    const float s1 = smem[SIGL + tl * 3 + 1];
    const float s2 = smem[SIGL + tl * 3 + 2];
    const size_t t = (size_t)t0 + tl;
    const float a0 = xt[t * 3 + 0], a1 = xt[t * 3 + 1], a2 = xt[t * 3 + 2];

    float acc[16];
#pragma unroll
    for (int i = 0; i < 16; ++i) acc[i] = 0.f;
    float l = 0.f;

    // stage tiles 0,1 (yc: 512 float4/tile; xc: 48 float4/tile)
    {
        float4 y0 = ycG[tid], y1 = ycG[512 + tid];
        float4 xq0, xq1;
        if (tid < 48) { xq0 = xcG[tid]; xq1 = xcG[48 + tid]; }
        ((float4*)(smem + YCS))[tid] = y0;
        ((float4*)(smem + YCS + 2048))[tid] = y1;
        if (tid < 48) {
            ((float4*)(smem + XCS))[tid] = xq0;
            ((float4*)(smem + XCS + 192))[tid] = xq1;
        }
    }
    __syncthreads();

    for (int tile = 0; tile < 16; ++tile) {
        float4 yn, xn;
        if (tile < 14) {                  // prefetch tile+2 (distance 2)
            yn = ycG[(tile + 2) * 512 + tid];
            if (tid < 48) xn = xcG[(tile + 2) * 48 + tid];
        }

        const float* yb = smem + YCS + (tile & 1) * 2048;
        const float* xb = smem + XCS + (tile & 1) * 192;
#pragma unroll
        for (int i = 0; i < 8; ++i) {
            const int nn = w * 8 + i;
            float d0 = xb[nn * 3 + 0] - a0;
            float d1 = xb[nn * 3 + 1] - a1;
            float d2 = xb[nn * 3 + 2] - a2;
            float pp = fmaf(s0, d0 * d0, fmaf(s1, d1 * d1, s2 * (d2 * d2)));
            float e = exp2f(-pp);
            l += e;
            const float4* yv = (const float4*)(yb + nn * DYY + dg * 16);
            float4 q0 = yv[0], q1 = yv[1], q2 = yv[2], q3 = yv[3];
            acc[0]  = fmaf(e, q0.x, acc[0]);
            acc[1]  = fmaf(e, q0.y, acc[1]);
            acc[2]  = fmaf(e, q0.z, acc[2]);
            acc[3]  = fmaf(e, q0.w, acc[3]);
            acc[4]  = fmaf(e, q1.x, acc[4]);
            acc[5]  = fmaf(e, q1.y, acc[5]);
            acc[6]  = fmaf(e, q1.z, acc[6]);
            acc[7]  = fmaf(e, q1.w, acc[7]);
            acc[8]  = fmaf(e, q2.x, acc[8]);
            acc[9]  = fmaf(e, q2.y, acc[9]);
            acc[10] = fmaf(e, q2.z, acc[10]);
            acc[11] = fmaf(e, q2.w, acc[11]);
            acc[12] = fmaf(e, q3.x, acc[12]);
            acc[13] = fmaf(e, q3.y, acc[13]);
            acc[14] = fmaf(e, q3.z, acc[14]);
            acc[15] = fmaf(e, q3.w, acc[15]);
        }
        __syncthreads();                  // tile reads done
        if (tile < 14) {                  // write tile+2 into the freed buffer;
            ((float4*)(smem + YCS + (tile & 1) * 2048))[tid] = yn;   // readers are
            if (tid < 48)                                            // fenced by the
                ((float4*)(smem + XCS + (tile & 1) * 192))[tid] = xn; // next barrier
        }
    }

    // ---- two-stage combine (4 slots, stride 33), normalize, write ----
    if (w >= 4) {                         // stage A: waves 4..7 deposit
#pragma unroll
        for (int i = 0; i < 16; ++i)
            smem[((w - 4) * 32 + tl) * 33 + dg * 16 + i] = acc[i];
        if (dg == 0) smem[SL + (w - 4) * 32 + tl] = l;
    }
    __syncthreads();
    if (w < 4) {                          // stage B: waves 0..3 accumulate
#pragma unroll
        for (int i = 0; i < 16; ++i)
            smem[(w * 32 + tl) * 33 + dg * 16 + i] += acc[i];
        if (dg == 0) smem[SL + w * 32 + tl] += l;
    }
    __syncthreads();

#pragma unroll
    for (int idx = 0; idx < 1024; idx += 512) {
        const int ii = idx + tid;
        const int rtl = ii >> 5, d = ii & 31;
        float s = 0.f, lsum = 0.f;
#pragma unroll
        for (int ww = 0; ww < 4; ++ww) {
            s += smem[(ww * 32 + rtl) * 33 + d];
            lsum += smem[SL + ww * 32 + rtl];
        }
        out[(size_t)(t0 + rtl) * DYY + d] = s / lsum;
    }
}

extern "C" void kernel_launch(void* const* d_in, const int* in_sizes, int n_in,
                              void* d_out, int out_size, void* d_ws, size_t ws_size,
                              hipStream_t stream) {
    const float* xc = (const float*)d_in[0];
    const float* yc = (const float*)d_in[1];
    const float* xt = (const float*)d_in[2];
    const float* W0 = (const float*)d_in[3];
    const float* b0 = (const float*)d_in[4];
    const float* W1 = (const float*)d_in[5];
    const float* b1 = (const float*)d_in[6];
    const float* W2 = (const float*)d_in[7];
    const float* b2 = (const float*)d_in[8];
    const float* W3 = (const float*)d_in[9];
    const float* b3 = (const float*)d_in[10];
    float* out = (float*)d_out;

    k_fused<<<dim3(BB * NTT / 32), dim3(512), 0, stream>>>(xc, yc, xt, W0, b0,
                                                           W1, b1, W2, b2, W3,
                                                           b3, out);
}